// Round 2
// baseline (345.269 us; speedup 1.0000x reference)
//
#include <hip/hip_runtime.h>

typedef unsigned short ushort_t;
typedef _Float16 half8 __attribute__((ext_vector_type(8)));
typedef short short8 __attribute__((ext_vector_type(8)));
typedef float floatx4 __attribute__((ext_vector_type(4)));

#define NCC 65536
#define NPP 1024
#define DD 256

static __device__ __forceinline__ ushort_t f2h_bits(float x) {
  _Float16 h = (_Float16)x;
  return __builtin_bit_cast(ushort_t, h);
}
static __device__ __forceinline__ ushort_t f2bf_bits(float x) {
  unsigned u = __builtin_bit_cast(unsigned, x);
  unsigned r = (u + 0x7FFFu + ((u >> 16) & 1u)) >> 16;
  return (ushort_t)r;
}

// async global->LDS DMA, 16B per lane; LDS dest = wave-uniform base + lane*16
static __device__ __forceinline__ void dma16(const void* g, void* l) {
  __builtin_amdgcn_global_load_lds((const __attribute__((address_space(1))) unsigned int*)g,
                                   (__attribute__((address_space(3))) unsigned int*)l, 16, 0, 0);
}

// ---------------------------------------------------------------------------
// K0: transpose Wq/Wk (fp32 [k][n]) -> WT (f16 [n][k]) with XOR-8 group
// swizzle on k so that contiguous DMA staging is bank-balanced for MFMA frags.
// stored half-index: k' = k XOR ((n & 7) << 3)
// ---------------------------------------------------------------------------
__global__ __launch_bounds__(256) void wt_prep(const float* __restrict__ Wq,
                                               const float* __restrict__ Wk,
                                               ushort_t* __restrict__ WqT,
                                               ushort_t* __restrict__ WkT) {
  __shared__ __align__(16) ushort_t lt[64][80];
  const float* W = blockIdx.y ? Wk : Wq;
  ushort_t* WT = blockIdx.y ? WkT : WqT;
  const int k0 = ((int)blockIdx.x & 3) * 64, n0 = ((int)blockIdx.x >> 2) * 64;
  const int t = threadIdx.x;
#pragma unroll
  for (int i = 0; i < 4; i++) {
    int f = t + 256 * i;
    int k = f >> 4, j = (f & 15) * 4;
    const float4 v = *(const float4*)&W[(size_t)(k0 + k) * DD + n0 + j];
    lt[j + 0][k] = f2h_bits(v.x);
    lt[j + 1][k] = f2h_bits(v.y);
    lt[j + 2][k] = f2h_bits(v.z);
    lt[j + 3][k] = f2h_bits(v.w);
  }
  __syncthreads();
#pragma unroll
  for (int i = 0; i < 2; i++) {
    int f = t + 256 * i;
    int nl = f >> 3, grp = f & 7;
    int n = n0 + nl;
    int kp = k0 + ((grp ^ (n & 7)) * 8);
    *(uint4*)&WT[(size_t)n * DD + kp] = *(const uint4*)&lt[nl][grp * 8];
  }
}

// ---------------------------------------------------------------------------
// K1: fused GEMM producing keyf (scaled, swizzled) and query (plain), f16.
// B panel (W^T) staged via global_load_lds from pre-swizzled WT.
// kf16 is stored with k' = k XOR ((c & 7) << 3) so attn DMA staging is
// contiguous AND MFMA A-frag reads are bank-balanced.
// ---------------------------------------------------------------------------
__global__ __launch_bounds__(256) void prep_gemm(
    const float* __restrict__ box_feat, const float* __restrict__ points_feat,
    const float* __restrict__ centers, const float* __restrict__ scales,
    const ushort_t* __restrict__ WqT, const ushort_t* __restrict__ WkT,
    const float* __restrict__ bq, const float* __restrict__ bk,
    ushort_t* __restrict__ q_out, ushort_t* __restrict__ kf_out,
    float* __restrict__ xs, float* __restrict__ ys) {
  __shared__ __align__(16) ushort_t lds_a[64][264];  // A rows (m=64, k=256), pad 8
  __shared__ __align__(16) ushort_t lds_b[64 * 256]; // W^T panel (n=64, k=256), swizzled
  __shared__ float lds_s[64];

  const int t = threadIdx.x;
  const bool isQ = (blockIdx.x >= (NCC / 64));
  const int row0 = isQ ? ((int)blockIdx.x - NCC / 64) * 64 : (int)blockIdx.x * 64;
  const float* In = isQ ? points_feat : box_feat;
  const ushort_t* WT = isQ ? WqT : WkT;
  const float* Bi = isQ ? bq : bk;
  ushort_t* Out = isQ ? q_out : kf_out;
  const int swzm = isQ ? 0 : 0x38;

  if (t < 64) {
    float s = 1.0f;
    if (!isQ) {
      int c = row0 + t;
      float stride = centers[c * 4 + 3];
      int lvl = (int)(log2f(stride) + 0.5f) - 3;
      lvl = lvl < 0 ? 0 : (lvl > 4 ? 4 : lvl);
      s = scales[lvl];
      float hf = floorf(centers[c * 4 + 2] * 0.5f);
      ys[c] = centers[c * 4 + 0] + hf;
      xs[c] = centers[c * 4 + 1] + hf;
    }
    lds_s[t] = s;
  }
  __syncthreads();

  // stage A: 64 rows x 256 cols fp32 -> scaled f16 (padded rows)
#pragma unroll
  for (int i = 0; i < 16; i++) {
    int f = t + 256 * i;
    int r = f >> 6;
    int c4 = (f & 63) * 4;
    const float4 v = *(const float4*)&In[(size_t)(row0 + r) * DD + c4];
    float s = lds_s[r];
    ushort_t h0 = f2h_bits(v.x * s), h1 = f2h_bits(v.y * s);
    ushort_t h2 = f2h_bits(v.z * s), h3 = f2h_bits(v.w * s);
    *(uint2*)&lds_a[r][c4] =
        make_uint2((unsigned)h0 | ((unsigned)h1 << 16), (unsigned)h2 | ((unsigned)h3 << 16));
  }

  const int w = t >> 6, lane = t & 63, qd = lane >> 4, n = lane & 15;
  const int sw8 = (n & 7) * 8;

  for (int g = 0; g < 4; ++g) {
    __syncthreads();  // lds_b reusable; also covers A-stage completion at g=0
    // stage W^T panel rows g*64..g*64+64 (32KB contiguous) via DMA
#pragma unroll
    for (int j = 0; j < 8; ++j) {
      int sg = w * 8 + j;
      dma16(&WT[(size_t)g * 64 * DD + sg * 512 + lane * 8], &lds_b[sg * 512 + lane * 8]);
    }
    __syncthreads();

    floatx4 acc[4] = {};
#pragma unroll
    for (int s = 0; s < 8; s++) {
      half8 af = __builtin_bit_cast(half8, *(const uint4*)&lds_a[w * 16 + n][s * 32 + qd * 8]);
      int off = (s * 32 + qd * 8) ^ sw8;
#pragma unroll
      for (int nt = 0; nt < 4; ++nt) {
        half8 bf = __builtin_bit_cast(half8, *(const uint4*)&lds_b[(nt * 16 + n) * 256 + off]);
        acc[nt] = __builtin_amdgcn_mfma_f32_16x16x32_f16(af, bf, acc[nt], 0, 0, 0);
      }
    }
    // epilogue: C/D layout row=4*qd+r, col=lane&15; kf gets XOR swizzle
#pragma unroll
    for (int nt = 0; nt < 4; ++nt) {
#pragma unroll
      for (int r = 0; r < 4; r++) {
        int row = row0 + w * 16 + qd * 4 + r;
        int col = g * 64 + nt * 16 + n;
        int colS = col ^ (swzm & ((row & 7) << 3));
        Out[(size_t)row * DD + colS] = f2h_bits(acc[nt][r] + Bi[col]);
      }
    }
  }
}

// ---------------------------------------------------------------------------
// K2: transpose box_feat (fp32 [NC][256]) -> vT (bf16 [256][NC])
// ---------------------------------------------------------------------------
__global__ __launch_bounds__(256) void transpose_v(const float* __restrict__ box_feat,
                                                   ushort_t* __restrict__ vT) {
  __shared__ __align__(16) ushort_t lt[64][72];
  const int t = threadIdx.x;
  const int c0 = blockIdx.x * 64, d0 = blockIdx.y * 64;
#pragma unroll
  for (int i = 0; i < 4; i++) {
    int f = t + 256 * i;
    int c = f >> 4;
    int j = (f & 15) * 4;
    const float4 v = *(const float4*)&box_feat[(size_t)(c0 + c) * DD + d0 + j];
    lt[j + 0][c] = f2bf_bits(v.x);
    lt[j + 1][c] = f2bf_bits(v.y);
    lt[j + 2][c] = f2bf_bits(v.z);
    lt[j + 3][c] = f2bf_bits(v.w);
  }
  __syncthreads();
#pragma unroll
  for (int i = 0; i < 4; i++) {
    int f = t + 256 * i;
    int d = f >> 4;
    int j = (f & 15) * 4;
    *(uint2*)&vT[(size_t)(d0 + d) * NCC + c0 + j] = *(const uint2*)&lt[d][j];
  }
}

// ---------------------------------------------------------------------------
// K3: fused attention. Block = 4 waves; each wave owns 32 points (2 MFMA
// p-tiles, qfr + macc register-resident). Grid (64 chunks, 8 p-groups):
// all 8 blocks of chunk c land on XCD c%8 -> chunk tiles live in one L2.
// Per iter: DMA-stage 32 candidates (kf 16KB swizzled + vT 16KB), QK f16 MFMA
// (each af read feeds 2 MFMAs), fixed-base-50 exp, PV bf16 MFMA (each b2 read
// feeds 2 MFMAs). Partials -> global atomics.
// ---------------------------------------------------------------------------
__global__ __launch_bounds__(256, 2) void attn_kernel(
    const ushort_t* __restrict__ qf16, const ushort_t* __restrict__ kf16,
    const ushort_t* __restrict__ vT, const float* __restrict__ xs,
    const float* __restrict__ ys, const float* __restrict__ boxes,
    float* __restrict__ acc_out, float* __restrict__ den_out) {
  __shared__ __align__(16) ushort_t lds_k[32 * 256];   // keyf tile [c][k'], swizzled
  __shared__ __align__(16) ushort_t lds_v[256 * 32];   // vT tile [d][c]
  __shared__ __align__(16) ushort_t lds_p[4][32][40];  // per-wave P^T [p][c] bf16
  __shared__ __align__(16) float2 lds_xy[32];

  const int t = threadIdx.x;
  const int w = t >> 6, lane = t & 63, qd = lane >> 4, n = lane & 15;
  const int p0w = blockIdx.y * 128 + w * 32;
  const int cchunk = blockIdx.x * 1024;
  const int sw8 = (n & 7) * 8;

  // resident query B-frags for 2 p-tiles + their boxes
  half8 qfr[2][8];
  float4 bxv[2];
#pragma unroll
  for (int pt = 0; pt < 2; ++pt) {
    int p = p0w + pt * 16 + n;
#pragma unroll
    for (int s = 0; s < 8; s++)
      qfr[pt][s] = __builtin_bit_cast(half8, *(const uint4*)&qf16[(size_t)p * DD + s * 32 + qd * 8]);
    bxv[pt] = *(const float4*)&boxes[p * 4];
  }

  floatx4 macc[2][16] = {};
  float dsum0 = 0.f, dsum1 = 0.f;

  for (int it = 0; it < 32; ++it) {
    const int cb = cchunk + it * 32;
    // DMA staging: kf tile = contiguous 16KB (swizzle is within rows);
    // vT tile = 256 rows x 64B gather
#pragma unroll
    for (int j = 0; j < 4; ++j) {
      int sg = w * 4 + j;
      dma16(&kf16[(size_t)cb * DD + sg * 512 + lane * 8], &lds_k[sg * 512 + lane * 8]);
      int d = sg * 16 + (lane >> 2);
      dma16(&vT[(size_t)d * NCC + cb + (lane & 3) * 8], &lds_v[d * 32 + (lane & 3) * 8]);
    }
    if (t < 32) lds_xy[t] = make_float2(xs[cb + t], ys[cb + t]);
    __syncthreads();

    // QK^T: two 16-candidate tiles x two 16-point tiles
#pragma unroll
    for (int t2 = 0; t2 < 2; ++t2) {
      floatx4 a0 = {}, a1 = {};
      const ushort_t* krow = &lds_k[(t2 * 16 + n) * 256];
#pragma unroll
      for (int s = 0; s < 8; s++) {
        half8 af = __builtin_bit_cast(half8, *(const uint4*)&krow[(s * 32 + qd * 8) ^ sw8]);
        a0 = __builtin_amdgcn_mfma_f32_16x16x32_f16(af, qfr[0][s], a0, 0, 0, 0);
        a1 = __builtin_amdgcn_mfma_f32_16x16x32_f16(af, qfr[1][s], a1, 0, 0, 0);
      }
      unsigned pk00 = 0, pk01 = 0, pk10 = 0, pk11 = 0;
#pragma unroll
      for (int r = 0; r < 4; r++) {
        int cl = t2 * 16 + qd * 4 + r;
        float2 xy = lds_xy[cl];
        // pt 0
        {
          float mn = fminf(fminf(xy.x - bxv[0].x, xy.y - bxv[0].y),
                           fminf(bxv[0].z - xy.x, bxv[0].w - xy.y));
          float sim = fminf(fmaxf(a0[r], -50.f), 50.f);
          float e = (mn > 0.f) ? exp2f((sim - 50.f) * 1.44269504f) : 0.f;
          dsum0 += e;
          unsigned b = (unsigned)f2bf_bits(e);
          if (r == 0) pk00 = b;
          else if (r == 1) pk00 |= b << 16;
          else if (r == 2) pk01 = b;
          else pk01 |= b << 16;
        }
        // pt 1
        {
          float mn = fminf(fminf(xy.x - bxv[1].x, xy.y - bxv[1].y),
                           fminf(bxv[1].z - xy.x, bxv[1].w - xy.y));
          float sim = fminf(fmaxf(a1[r], -50.f), 50.f);
          float e = (mn > 0.f) ? exp2f((sim - 50.f) * 1.44269504f) : 0.f;
          dsum1 += e;
          unsigned b = (unsigned)f2bf_bits(e);
          if (r == 0) pk10 = b;
          else if (r == 1) pk10 |= b << 16;
          else if (r == 2) pk11 = b;
          else pk11 |= b << 16;
        }
      }
      *(uint2*)&lds_p[w][n][t2 * 16 + qd * 4] = make_uint2(pk00, pk01);
      *(uint2*)&lds_p[w][16 + n][t2 * 16 + qd * 4] = make_uint2(pk10, pk11);
    }
    // same-wave LDS RAW: drain our ds_writes before reading lds_p
    __asm__ volatile("s_waitcnt lgkmcnt(0)" ::: "memory");

    short8 a20 = __builtin_bit_cast(short8, *(const uint4*)&lds_p[w][n][qd * 8]);
    short8 a21 = __builtin_bit_cast(short8, *(const uint4*)&lds_p[w][16 + n][qd * 8]);
#pragma unroll
    for (int dt = 0; dt < 16; ++dt) {
      short8 b2 = __builtin_bit_cast(short8, *(const uint4*)&lds_v[(dt * 16 + n) * 32 + qd * 8]);
      macc[0][dt] = __builtin_amdgcn_mfma_f32_16x16x32_bf16(a20, b2, macc[0][dt], 0, 0, 0);
      macc[1][dt] = __builtin_amdgcn_mfma_f32_16x16x32_bf16(a21, b2, macc[1][dt], 0, 0, 0);
    }
    __syncthreads();  // protect lds_k/lds_v/lds_xy before next staging
  }

  // denom: lanes l, l^16, l^32, l^48 share the same point column
  dsum0 += __shfl_xor(dsum0, 16, 64);
  dsum0 += __shfl_xor(dsum0, 32, 64);
  dsum1 += __shfl_xor(dsum1, 16, 64);
  dsum1 += __shfl_xor(dsum1, 32, 64);
  if (lane < 16) {
    atomicAdd(&den_out[p0w + n], dsum0);
    atomicAdd(&den_out[p0w + 16 + n], dsum1);
  }

  // merge partials: C/D layout row(p)=4qd+r, col(d)=dt*16+n
#pragma unroll
  for (int pt = 0; pt < 2; ++pt) {
#pragma unroll
    for (int dt = 0; dt < 16; ++dt) {
#pragma unroll
      for (int r = 0; r < 4; r++) {
        atomicAdd(&acc_out[(size_t)(p0w + pt * 16 + qd * 4 + r) * DD + dt * 16 + n],
                  macc[pt][dt][r]);
      }
    }
  }
}

// ---------------------------------------------------------------------------
// K4: out = points_feat + acc/den (guard empty columns)
// ---------------------------------------------------------------------------
__global__ void finalize(const float* __restrict__ points_feat, const float* __restrict__ acc,
                         const float* __restrict__ den, float* __restrict__ out) {
  int p = blockIdx.x, d = threadIdx.x;
  float dn = den[p];
  float m = (dn > 0.f) ? acc[p * DD + d] / dn : 0.f;
  out[p * DD + d] = points_feat[p * DD + d] + m;
}

extern "C" void kernel_launch(void* const* d_in, const int* in_sizes, int n_in, void* d_out,
                              int out_size, void* d_ws, size_t ws_size, hipStream_t stream) {
  const float* points_feat = (const float*)d_in[0];
  const float* box_feat = (const float*)d_in[1];
  const float* centers = (const float*)d_in[2];
  const float* boxes = (const float*)d_in[3];
  const float* Wq = (const float*)d_in[4];
  const float* bq = (const float*)d_in[5];
  const float* Wk = (const float*)d_in[6];
  const float* bk = (const float*)d_in[7];
  const float* scales = (const float*)d_in[8];

  // workspace layout (~69.5 MB)
  ushort_t* ws_q = (ushort_t*)d_ws;                   // 1024*256 f16
  ushort_t* ws_kf = ws_q + (size_t)NPP * DD;          // 65536*256 f16 (swizzled)
  ushort_t* ws_vT = ws_kf + (size_t)NCC * DD;         // 256*65536 bf16
  float* ws_xs = (float*)(ws_vT + (size_t)NCC * DD);  // 65536 f32
  float* ws_ys = ws_xs + NCC;                         // 65536 f32
  float* ws_acc = ws_ys + NCC;                        // 1024*256 f32
  float* ws_den = ws_acc + (size_t)NPP * DD;          // 1024 f32
  ushort_t* ws_wqT = (ushort_t*)(ws_den + NPP);       // 256*256 f16 (swizzled)
  ushort_t* ws_wkT = ws_wqT + DD * DD;                // 256*256 f16 (swizzled)

  hipMemsetAsync(ws_acc, 0, ((size_t)NPP * DD + NPP) * sizeof(float), stream);
  wt_prep<<<dim3(16, 2), 256, 0, stream>>>(Wq, Wk, ws_wqT, ws_wkT);
  prep_gemm<<<NCC / 64 + NPP / 64, 256, 0, stream>>>(box_feat, points_feat, centers, scales,
                                                     ws_wqT, ws_wkT, bq, bk, ws_q, ws_kf, ws_xs,
                                                     ws_ys);
  transpose_v<<<dim3(NCC / 64, DD / 64), 256, 0, stream>>>(box_feat, ws_vT);
  attn_kernel<<<dim3(64, 8), 256, 0, stream>>>(ws_q, ws_kf, ws_vT, ws_xs, ws_ys, boxes, ws_acc,
                                               ws_den);
  finalize<<<NPP, DD, 0, stream>>>(points_feat, ws_acc, ws_den, (float*)d_out);
}